// Round 1
// baseline (418.837 us; speedup 1.0000x reference)
//
#include <hip/hip_runtime.h>
#include <hip/hip_bf16.h>
#include <math.h>

#define B_ 2
#define H_ 12
#define S_ 1024
#define D_ 128
#define BH_ (B_ * H_)
#define TQ 32
#define TK 32
#define NW 4
#define SCALE 0.08838834764831843f

#define QPAD 16
#define QROWS (S_ + QPAD)          /* 1040 */
#define KHD 768                    /* 6 taps * 128 = GEMM contraction dim */

/* merged prepass grid segmentation */
#define NB_KH   18432              /* 24*1024*6*32 / 256 */
#define NB_QP   3120               /* 24*1040*128 / 1024 */
#define NB_VT   3072               /* 24*32*4 */
#define NB_CORR 384                /* 24*16 */
#define NB_PREP (NB_KH + NB_QP + NB_VT + NB_CORR)

typedef __attribute__((ext_vector_type(8))) short short8;
typedef __attribute__((ext_vector_type(4))) float floatx4;

__device__ __forceinline__ unsigned short f2b(float f) {
    return __builtin_bit_cast(unsigned short, __float2bfloat16(f));
}

// ---- merged prepass ---------------------------------------------------------
// section 1: Khat[bh][k][i][d] = sum_j W[h][i][j]*SCALE * K[k+j-5][d]  (bf16)
// section 2: Qp = Q -> bf16 with 16 zero rows of top padding
// section 3: Vp[bh][d][32g + qd*8+nt*4+reg] = V[32g + nt*16+qd*4+reg][d] (bf16,
//            sigma-permuted so swapped-MFMA P fragments feed PV directly)
// section 4: Corr[bh][q][d] = sum_{i,j: j-i>d} Ws[i,j] * (Q[q-5+i].K[q-5+i+(j-i-d)])
__global__ __launch_bounds__(256) void prep_kernel(
    const float* __restrict__ Q, const float* __restrict__ K,
    const float* __restrict__ V, const float* __restrict__ W,
    unsigned short* __restrict__ Qp, unsigned short* __restrict__ Kh,
    unsigned short* __restrict__ Vp, float* __restrict__ Corr)
{
    __shared__ union {
        float vt_ls[32][33];
        float band[69][16];
    } sm;
    const int blk = blockIdx.x;
    const int tid = threadIdx.x;

    if (blk < NB_KH) {
        const int idx = blk * 256 + tid;
        const int d4 = idx & 31;
        const int t2 = idx >> 5;
        const int i  = t2 % 6;
        const int t3 = t2 / 6;
        const int k  = t3 & (S_ - 1);
        const int bh = t3 >> 10;
        const int h  = bh % H_;
        const float* Kb = K + (size_t)bh * S_ * D_ + d4 * 4;
        const float* wrow = W + h * 66 + i * 11;
        float ax = 0.f, ay = 0.f, az = 0.f, aw = 0.f;
        #pragma unroll
        for (int j = 0; j < 11; ++j) {
            const int kr = k + j - 5;
            if (kr >= 0 && kr < S_) {
                const float w = wrow[j] * SCALE;
                const float4 kv = *(const float4*)(Kb + (size_t)kr * D_);
                ax += w * kv.x; ay += w * kv.y; az += w * kv.z; aw += w * kv.w;
            }
        }
        ushort4 o; o.x = f2b(ax); o.y = f2b(ay); o.z = f2b(az); o.w = f2b(aw);
        *(ushort4*)(Kh + (((size_t)bh * S_ + k) * 6 + i) * D_ + d4 * 4) = o;
    } else if (blk < NB_KH + NB_QP) {
        const int idx = (blk - NB_KH) * 256 + tid;
        const size_t e0 = (size_t)idx * 4;
        const int bh = (int)(e0 / ((size_t)QROWS * D_));
        const int rem = (int)(e0 - (size_t)bh * QROWS * D_);
        const int r = rem / D_;
        const int d = rem - r * D_;
        const int sr = r - QPAD;
        float4 v = make_float4(0.f, 0.f, 0.f, 0.f);
        if (sr >= 0 && sr < S_)
            v = *(const float4*)(Q + ((size_t)bh * S_ + sr) * D_ + d);
        ushort4 o; o.x = f2b(v.x); o.y = f2b(v.y); o.z = f2b(v.z); o.w = f2b(v.w);
        *(ushort4*)(Qp + ((size_t)bh * QROWS + r) * D_ + d) = o;
    } else if (blk < NB_KH + NB_QP + NB_VT) {
        const int b2 = blk - (NB_KH + NB_QP);
        const int dt = b2 & 3, ktl = (b2 >> 2) & 31, bh = b2 >> 7;
        const int lk = tid >> 3, ld = (tid & 7) * 4;
        const float4 v4 = *(const float4*)(V + ((size_t)bh * S_ + ktl * 32 + lk) * D_ + dt * 32 + ld);
        sm.vt_ls[lk][ld + 0] = v4.x; sm.vt_ls[lk][ld + 1] = v4.y;
        sm.vt_ls[lk][ld + 2] = v4.z; sm.vt_ls[lk][ld + 3] = v4.w;
        __syncthreads();
        const int lk2 = tid >> 3, lc = (tid & 7) * 4;
        const int pb = ((lc >> 3) << 2) | (((lc >> 2) & 1) << 4);   // sigma permutation
        ushort4 o;
        o.x = f2b(sm.vt_ls[pb + 0][lk2]); o.y = f2b(sm.vt_ls[pb + 1][lk2]);
        o.z = f2b(sm.vt_ls[pb + 2][lk2]); o.w = f2b(sm.vt_ls[pb + 3][lk2]);
        *(ushort4*)(Vp + ((size_t)bh * D_ + dt * 32 + lk2) * S_ + ktl * 32 + lc) = o;
    } else {
        const int cb = blk - (NB_KH + NB_QP + NB_VT);
        const int bh = cb >> 4, q0c = (cb & 15) * 64;
        const int h = bh % H_;
        // step 1: raw superdiagonal band  band[r][dsl] = Q[q'].K[q'+dsl+1]
        for (int s = tid; s < 69 * 16; s += 256) {
            const int r = s >> 4, dsl = s & 15;
            float v = 0.f;
            if (dsl < 10) {
                const int qp = q0c - 5 + r, delta = dsl + 1;
                if (qp >= 0 && qp + delta < S_) {
                    const float4* qr = (const float4*)(Q + ((size_t)bh * S_ + qp) * D_);
                    const float4* kr = (const float4*)(K + ((size_t)bh * S_ + qp + delta) * D_);
                    #pragma unroll 8
                    for (int c = 0; c < 32; ++c) {
                        const float4 a = qr[c], b = kr[c];
                        v += a.x * b.x + a.y * b.y + a.z * b.z + a.w * b.w;
                    }
                }
            }
            sm.band[r][dsl] = v;
        }
        __syncthreads();
        // step 2: correction table
        for (int e = tid; e < 64 * 16; e += 256) {
            const int ql = e >> 4, d = e & 15;
            float v = 0.f;
            if (d <= 10) {
                for (int i2 = 0; i2 < 6; ++i2)
                    for (int j = i2 + d + 1; j < 11; ++j)
                        v += W[h * 66 + i2 * 11 + j] * SCALE * sm.band[ql + i2][j - i2 - d - 1];
            }
            Corr[((size_t)bh << 14) + ((size_t)(q0c + ql) << 4) + d] = v;
        }
    }
}

// ---- main fused kernel: factorized conv-attention ---------------------------
// logits[q,k] = Qtilde[q] . Khat[k]  (768-dim swapped MFMA)  -  Corr[q][q-k]
__global__ __launch_bounds__(256, 2) void conv_attn_mfma(
    const unsigned short* __restrict__ Qp,   // [24][1040][128] bf16
    const unsigned short* __restrict__ Kh,   // [24][1024][768] bf16
    const unsigned short* __restrict__ Vp,   // [24][128][1024] bf16 (permuted)
    const float* __restrict__ Corr,          // [24][1024][16]  f32
    float* __restrict__ O)                   // [24][1024][128] f32
{
    __shared__ __align__(16) float oacc[32][132];
    __shared__ float m_all[NW][32], l_all[NW][32], ms_s[32], inv_s[32];

    const int tid = threadIdx.x;
    const int wv = tid >> 6;
    const int ln = tid & 63;
    const int l15 = ln & 15;
    const int qd = ln >> 4;

    const int bid = blockIdx.x;
    const int wg  = (bid & 7) * 96 + (bid >> 3);   // XCD-contiguous: 3 bh per XCD
    const int bh  = wg >> 5;
    const int qt  = (S_ / TQ - 1) - (wg & 31);     // heavy tiles first per XCD
    const int q0  = qt * TQ;

    const unsigned short* Qb0 = Qp + ((size_t)bh * QROWS + q0 + 11 + l15) * D_ + qd * 8;
    const unsigned short* Qb1 = Qb0 + 16 * D_;
    const unsigned short* Khb = Kh + (size_t)bh * S_ * KHD;
    const unsigned short* Vb  = Vp + ((size_t)bh * D_ + l15) * S_ + qd * 8;
    const float* Cb = Corr + ((size_t)bh << 14);

    floatx4 acc[2][8];
    #pragma unroll
    for (int mt = 0; mt < 2; ++mt)
        #pragma unroll
        for (int nd = 0; nd < 8; ++nd)
            acc[mt][nd] = (floatx4){0.f, 0.f, 0.f, 0.f};
    float m_run[2] = {-INFINITY, -INFINITY};
    float l_run[2] = {0.f, 0.f};

    for (int kt = wv; kt <= qt; kt += NW) {
        const int k0 = kt * TK;
        const unsigned short* A0 = Khb + (size_t)(k0 + l15) * KHD + qd * 8;
        const unsigned short* A1 = A0 + 16 * KHD;

        short8 vf[8];
        #pragma unroll
        for (int nd = 0; nd < 8; ++nd)
            vf[nd] = *(const short8*)(Vb + (size_t)nd * 16 * S_ + k0);

        floatx4 sc_[2][2];   // [nt][mt]: rows = k (qd*4+reg), cols = q (l15)
        #pragma unroll
        for (int nt = 0; nt < 2; ++nt)
            #pragma unroll
            for (int mt = 0; mt < 2; ++mt)
                sc_[nt][mt] = (floatx4){0.f, 0.f, 0.f, 0.f};

        // 768-dim contraction: c = i*4 + kc, all offsets fold to immediates
        #pragma unroll
        for (int c = 0; c < 24; ++c) {
            const short8 a0 = *(const short8*)(A0 + c * 32);
            const short8 a1 = *(const short8*)(A1 + c * 32);
            const short8 b0 = *(const short8*)(Qb0 + (c >> 2) * D_ + (c & 3) * 32);
            const short8 b1 = *(const short8*)(Qb1 + (c >> 2) * D_ + (c & 3) * 32);
            sc_[0][0] = __builtin_amdgcn_mfma_f32_16x16x32_bf16(a0, b0, sc_[0][0], 0, 0, 0);
            sc_[0][1] = __builtin_amdgcn_mfma_f32_16x16x32_bf16(a0, b1, sc_[0][1], 0, 0, 0);
            sc_[1][0] = __builtin_amdgcn_mfma_f32_16x16x32_bf16(a1, b0, sc_[1][0], 0, 0, 0);
            sc_[1][1] = __builtin_amdgcn_mfma_f32_16x16x32_bf16(a1, b1, sc_[1][1], 0, 0, 0);
        }

        // ---- online softmax; lane l15 = q-row, elements span k ------------
        const bool need_corr = (kt >= qt - 1);
        float al[2];
        short8 pfrag[2];
        #pragma unroll
        for (int mt = 0; mt < 2; ++mt) {
            const int qrow = q0 + mt * 16 + l15;
            float lg[8];
            float mx = -1e30f;
            #pragma unroll
            for (int nt = 0; nt < 2; ++nt)
                #pragma unroll
                for (int rg = 0; rg < 4; ++rg) {
                    const int kcol = k0 + nt * 16 + qd * 4 + rg;
                    float v = sc_[nt][mt][rg];
                    if (need_corr) {
                        const int dd = qrow - kcol;
                        if (dd >= 0 && dd <= 10) v -= Cb[(qrow << 4) + dd];
                    }
                    const int jj = nt * 4 + rg;
                    lg[jj] = (kcol <= qrow) ? v : -1e30f;
                    mx = fmaxf(mx, lg[jj]);
                }
            mx = fmaxf(mx, __shfl_xor(mx, 16));
            mx = fmaxf(mx, __shfl_xor(mx, 32));
            const float nm = fmaxf(m_run[mt], mx);
            al[mt] = __expf(m_run[mt] - nm);
            float sum = 0.f;
            short8 pbv;
            #pragma unroll
            for (int jj = 0; jj < 8; ++jj) {
                const float p = __expf(lg[jj] - nm);
                sum += p;
                pbv[jj] = (short)f2b(p);
            }
            sum += __shfl_xor(sum, 16);
            sum += __shfl_xor(sum, 32);
            l_run[mt] = l_run[mt] * al[mt] + sum;
            m_run[mt] = nm;
            pfrag[mt] = pbv;
        }

        // rescale accumulator: alpha for acc row qd*4+rg lives on lane qd*4+rg
        #pragma unroll
        for (int mt = 0; mt < 2; ++mt)
            #pragma unroll
            for (int rg = 0; rg < 4; ++rg) {
                const float af = __shfl(al[mt], qd * 4 + rg, 64);
                #pragma unroll
                for (int nd = 0; nd < 8; ++nd)
                    acc[mt][nd][rg] *= af;
            }

        // ---- P @ V via MFMA (pfrag element order matches permuted Vp) -----
        #pragma unroll
        for (int nd = 0; nd < 8; ++nd)
            #pragma unroll
            for (int mt = 0; mt < 2; ++mt)
                acc[mt][nd] = __builtin_amdgcn_mfma_f32_16x16x32_bf16(pfrag[mt], vf[nd], acc[mt][nd], 0, 0, 0);
    }

    // ---- merge the 4 waves' partials ---------------------------------------
    if (qd == 0) {
        m_all[wv][l15] = m_run[0]; m_all[wv][l15 + 16] = m_run[1];
        l_all[wv][l15] = l_run[0]; l_all[wv][l15 + 16] = l_run[1];
    }
    __syncthreads();
    if (tid < 32) {
        float ms = -INFINITY;
        #pragma unroll
        for (int w = 0; w < NW; ++w) ms = fmaxf(ms, m_all[w][tid]);
        float ls = 0.f;
        #pragma unroll
        for (int w = 0; w < NW; ++w) ls += __expf(m_all[w][tid] - ms) * l_all[w][tid];
        ms_s[tid] = ms;
        inv_s[tid] = 1.f / ls;
    }
    __syncthreads();
    for (int w = 0; w < NW; ++w) {
        if (wv == w) {
            #pragma unroll
            for (int mt = 0; mt < 2; ++mt) {
                #pragma unroll
                for (int rg = 0; rg < 4; ++rg) {
                    const int row = mt * 16 + qd * 4 + rg;
                    const float f = __expf(m_all[wv][row] - ms_s[row]);
                    #pragma unroll
                    for (int nd = 0; nd < 8; ++nd) {
                        const float val = acc[mt][nd][rg] * f;
                        if (w == 0) oacc[row][nd * 16 + l15] = val;
                        else        oacc[row][nd * 16 + l15] += val;
                    }
                }
            }
        }
        __syncthreads();
    }

    // ---- normalize + store --------------------------------------------------
    {
        const int r = tid >> 3;
        const int c0 = (tid & 7) * 16;
        const float inv = inv_s[r];
        float* orow = O + ((size_t)bh * S_ + q0 + r) * D_ + c0;
        #pragma unroll
        for (int g = 0; g < 4; ++g) {
            float4 o;
            o.x = oacc[r][c0 + g * 4 + 0] * inv;
            o.y = oacc[r][c0 + g * 4 + 1] * inv;
            o.z = oacc[r][c0 + g * 4 + 2] * inv;
            o.w = oacc[r][c0 + g * 4 + 3] * inv;
            *(float4*)(orow + g * 4) = o;
        }
    }
}

extern "C" void kernel_launch(void* const* d_in, const int* in_sizes, int n_in,
                              void* d_out, int out_size, void* d_ws, size_t ws_size,
                              hipStream_t stream) {
    const float* Q = (const float*)d_in[0];
    const float* K = (const float*)d_in[1];
    const float* V = (const float*)d_in[2];
    const float* W = (const float*)d_in[3];
    float* O = (float*)d_out;

    // ws layout (~52 MB)
    unsigned short* Qp = (unsigned short*)d_ws;                          // 24*1040*128*2 = 6,389,760
    unsigned short* Kh = (unsigned short*)((char*)d_ws + 6389760);       // 24*1024*768*2 = 37,748,736
    unsigned short* Vp = (unsigned short*)((char*)d_ws + 44138496);      // 24*128*1024*2 = 6,291,456
    float*          Cr = (float*)((char*)d_ws + 50429952);               // 24*1024*16*4  = 1,572,864

    prep_kernel<<<dim3(NB_PREP), dim3(256), 0, stream>>>(Q, K, V, W, Qp, Kh, Vp, Cr);
    conv_attn_mfma<<<dim3(BH_ * (S_ / TQ)), dim3(256), 0, stream>>>(Qp, Kh, Vp, Cr, O);
}

// Round 2
// 349.156 us; speedup vs baseline: 1.1996x; 1.1996x over previous
//
#include <hip/hip_runtime.h>
#include <hip/hip_bf16.h>
#include <math.h>

#define B_ 2
#define H_ 12
#define S_ 1024
#define D_ 128
#define BH_ (B_ * H_)
#define TQ 32
#define TK 32
#define NW 4
#define SCALE 0.08838834764831843f

#define QPAD 16
#define QROWS (S_ + QPAD)          /* 1040 */

/* merged prepass grid segmentation */
#define NB_KH   768                /* 24 bh * 32 k-tiles */
#define NB_QP   3120               /* 24*1040*128 / 1024 */
#define NB_VT   3072               /* 24*32*4 */
#define NB_CORR 384                /* 24*16 */
#define NB_PREP (NB_KH + NB_QP + NB_VT + NB_CORR)

typedef __attribute__((ext_vector_type(8))) short short8;
typedef __attribute__((ext_vector_type(4))) float floatx4;

__device__ __forceinline__ unsigned short f2b(float f) {
    return __builtin_bit_cast(unsigned short, __float2bfloat16(f));
}

// ---- merged prepass ---------------------------------------------------------
// KH: Khat fragment-major. KhF[bh*32+kt] is a 24576-ushort block laid out as
//     [c(24)][nt(2)][ln(64)][e(8)], holding
//     Khat[k = kt*32+nt*16+(ln&15)][col = c*32+(ln>>4)*8+e],
//     Khat[k][i*128+d] = sum_j W[h][i][j]*SCALE * K[k+j-5][d].
// QP: Qp = Q -> bf16 row-major with 16 zero rows of top padding.
// VT: VhF[bh*32+kt][nd(8)][ln(64)][e(8)] = V[k0+sigma(qd*8+e)][nd*16+l15]
//     (sigma-permuted so swapped-MFMA P fragments feed PV directly).
// CORR: Corr[bh][q][d] = sum_{i,j: j-i>d} Ws[i,j]*(Q[q-5+i].K[q-5+i+(j-i-d)])
__global__ __launch_bounds__(256) void prep_kernel(
    const float* __restrict__ Q, const float* __restrict__ K,
    const float* __restrict__ V, const float* __restrict__ W,
    unsigned short* __restrict__ Qp, unsigned short* __restrict__ KhF,
    unsigned short* __restrict__ VhF, float* __restrict__ Corr)
{
    __shared__ union {
        float vt_ls[32][33];
        float band[69][16];
        unsigned short khs[24576];   /* 48 KiB */
    } sm;
    const int blk = blockIdx.x;
    const int tid = threadIdx.x;

    if (blk < NB_KH) {
        // XCD-cluster: 3 bh per XCD so K rows stay in one L2
        const int wgk = (blk & 7) * 96 + (blk >> 3);
        const int bh = wgk >> 5, ktile = wgk & 31;
        const int h = bh % H_;
        const int k0 = ktile * 32;
        const float* Kb = K + (size_t)bh * S_ * D_;
        const float* Wh = W + h * 66;
        #pragma unroll
        for (int it = 0; it < 4; ++it) {
            const int p = tid + it * 256;        // 0..1023
            const int r = p >> 5;                // k-row in tile
            const int d0 = (p & 31) * 4;         // 0..124
            const int k = k0 + r;
            float a[6][4];
            #pragma unroll
            for (int i = 0; i < 6; ++i)
                #pragma unroll
                for (int t = 0; t < 4; ++t) a[i][t] = 0.f;
            #pragma unroll
            for (int j = 0; j < 11; ++j) {
                const int kr = k + j - 5;
                if (kr >= 0 && kr < S_) {
                    const float4 kv = *(const float4*)(Kb + (size_t)kr * D_ + d0);
                    #pragma unroll
                    for (int i = 0; i < 6; ++i) {
                        const float w = Wh[i * 11 + j] * SCALE;
                        a[i][0] += w * kv.x; a[i][1] += w * kv.y;
                        a[i][2] += w * kv.z; a[i][3] += w * kv.w;
                    }
                }
            }
            const int nt = r >> 4;
            const int ln = (((d0 & 31) >> 3) << 4) | (r & 15);
            const int e0 = d0 & 7;
            const int cc = d0 >> 5;
            #pragma unroll
            for (int i = 0; i < 6; ++i) {
                const int c = i * 4 + cc;
                ushort4 o;
                o.x = f2b(a[i][0]); o.y = f2b(a[i][1]);
                o.z = f2b(a[i][2]); o.w = f2b(a[i][3]);
                *(ushort4*)(&sm.khs[((c * 2 + nt) * 64 + ln) * 8 + e0]) = o;
            }
        }
        __syncthreads();
        const size_t obase = (size_t)wgk * 24576;
        #pragma unroll
        for (int it = 0; it < 12; ++it) {
            const int off = (tid + it * 256) * 8;
            *(short8*)(KhF + obase + off) = *(const short8*)(&sm.khs[off]);
        }
    } else if (blk < NB_KH + NB_QP) {
        const int idx = (blk - NB_KH) * 256 + tid;
        const size_t e0 = (size_t)idx * 4;
        const int bh = (int)(e0 / ((size_t)QROWS * D_));
        const int rem = (int)(e0 - (size_t)bh * QROWS * D_);
        const int r = rem / D_;
        const int d = rem - r * D_;
        const int sr = r - QPAD;
        float4 v = make_float4(0.f, 0.f, 0.f, 0.f);
        if (sr >= 0 && sr < S_)
            v = *(const float4*)(Q + ((size_t)bh * S_ + sr) * D_ + d);
        ushort4 o; o.x = f2b(v.x); o.y = f2b(v.y); o.z = f2b(v.z); o.w = f2b(v.w);
        *(ushort4*)(Qp + ((size_t)bh * QROWS + r) * D_ + d) = o;
    } else if (blk < NB_KH + NB_QP + NB_VT) {
        const int b2 = blk - (NB_KH + NB_QP);
        const int dt = b2 & 3, ktl = (b2 >> 2) & 31, bh = b2 >> 7;
        const int lk = tid >> 3, ld = (tid & 7) * 4;
        const float4 v4 = *(const float4*)(V + ((size_t)bh * S_ + ktl * 32 + lk) * D_ + dt * 32 + ld);
        sm.vt_ls[lk][ld + 0] = v4.x; sm.vt_ls[lk][ld + 1] = v4.y;
        sm.vt_ls[lk][ld + 2] = v4.z; sm.vt_ls[lk][ld + 3] = v4.w;
        __syncthreads();
        const int lk2 = tid >> 3, lc = (tid & 7) * 4;
        const int pb = ((lc >> 3) << 2) | (((lc >> 2) & 1) << 4);   // sigma
        const int d = dt * 32 + lk2;
        const int nd = d >> 4, l15v = d & 15;
        ushort4 o;
        o.x = f2b(sm.vt_ls[pb + 0][lk2]); o.y = f2b(sm.vt_ls[pb + 1][lk2]);
        o.z = f2b(sm.vt_ls[pb + 2][lk2]); o.w = f2b(sm.vt_ls[pb + 3][lk2]);
        const size_t addr = ((size_t)((bh * 32 + ktl) * 8 + nd) * 64
                             + (lc >> 3) * 16 + l15v) * 8 + (lc & 7);
        *(ushort4*)(VhF + addr) = o;
    } else {
        const int cb = blk - (NB_KH + NB_QP + NB_VT);
        const int bh = cb >> 4, q0c = (cb & 15) * 64;
        const int h = bh % H_;
        for (int s = tid; s < 69 * 16; s += 256) {
            const int r = s >> 4, dsl = s & 15;
            float v = 0.f;
            if (dsl < 10) {
                const int qp = q0c - 5 + r, delta = dsl + 1;
                if (qp >= 0 && qp + delta < S_) {
                    const float4* qr = (const float4*)(Q + ((size_t)bh * S_ + qp) * D_);
                    const float4* kr = (const float4*)(K + ((size_t)bh * S_ + qp + delta) * D_);
                    #pragma unroll 8
                    for (int c = 0; c < 32; ++c) {
                        const float4 a = qr[c], b = kr[c];
                        v += a.x * b.x + a.y * b.y + a.z * b.z + a.w * b.w;
                    }
                }
            }
            sm.band[r][dsl] = v;
        }
        __syncthreads();
        for (int e = tid; e < 64 * 16; e += 256) {
            const int ql = e >> 4, d = e & 15;
            float v = 0.f;
            if (d <= 10) {
                for (int i2 = 0; i2 < 6; ++i2)
                    for (int j = i2 + d + 1; j < 11; ++j)
                        v += W[h * 66 + i2 * 11 + j] * SCALE * sm.band[ql + i2][j - i2 - d - 1];
            }
            Corr[((size_t)bh << 14) + ((size_t)(q0c + ql) << 4) + d] = v;
        }
    }
}

// ---- main fused kernel: factorized conv-attention ---------------------------
// logits[q,k] = Qtilde[q] . Khat[k]  (768-dim swapped MFMA)  -  Corr[q][q-k]
__global__ __launch_bounds__(256, 3) void conv_attn_mfma(
    const unsigned short* __restrict__ Qp,   // [24][1040][128] bf16 row-major
    const unsigned short* __restrict__ KhF,  // fragment-major Khat
    const unsigned short* __restrict__ VhF,  // fragment-major permuted V
    const float* __restrict__ Corr,          // [24][1024][16]  f32
    float* __restrict__ O)                   // [24][1024][128] f32
{
    __shared__ __align__(16) union {
        unsigned short qlds[37 * 136];       // 10,064 B: Q rows q0-5..q0+31, 272B stride
        float oacc[32][132];                 // 16,896 B (reused after k-loop)
    } u;
    __shared__ float m_all[NW][32], l_all[NW][32], ms_s[32], inv_s[32];

    const int tid = threadIdx.x;
    const int wv = tid >> 6;
    const int ln = tid & 63;
    const int l15 = ln & 15;
    const int qd = ln >> 4;

    const int bid = blockIdx.x;
    const int wg  = (bid & 7) * 96 + (bid >> 3);   // XCD-contiguous: 3 bh per XCD
    const int bh  = wg >> 5;
    const int qt  = (S_ / TQ - 1) - (wg & 31);     // heavy tiles first per XCD
    const int q0  = qt * TQ;

    // ---- stage Q rows into LDS (once per block), coalesced ----------------
    for (int t = tid; t < 37 * 16; t += 256) {
        const int r = t >> 4, cb = t & 15;
        *(short8*)(&u.qlds[r * 136 + cb * 8]) =
            *(const short8*)(Qp + ((size_t)bh * QROWS + q0 + 11 + r) * D_ + cb * 8);
    }
    __syncthreads();

    const unsigned short* Khb = KhF + (size_t)(bh * 32) * 24576 + ln * 8;
    const unsigned short* Vhb = VhF + (size_t)(bh * 32) * 4096 + ln * 8;
    const float* Cb = Corr + ((size_t)bh << 14);
    const unsigned short* qb = &u.qlds[l15 * 136 + qd * 8];

    floatx4 acc[2][8];
    #pragma unroll
    for (int mt = 0; mt < 2; ++mt)
        #pragma unroll
        for (int nd = 0; nd < 8; ++nd)
            acc[mt][nd] = (floatx4){0.f, 0.f, 0.f, 0.f};
    float m_run[2] = {-INFINITY, -INFINITY};
    float l_run[2] = {0.f, 0.f};

    for (int kt = wv; kt <= qt; kt += NW) {
        const int k0 = kt * TK;
        const unsigned short* A = Khb + (size_t)kt * 24576;
        const unsigned short* Vt = Vhb + (size_t)kt * 4096;

        // V fragments: coalesced, independent -> issue early
        short8 vf[8];
        #pragma unroll
        for (int nd = 0; nd < 8; ++nd)
            vf[nd] = *(const short8*)(Vt + nd * 512);

        floatx4 sc_[2][2];   // [nt][mt]: rows = k (qd*4+rg), cols = q (l15)
        #pragma unroll
        for (int nt = 0; nt < 2; ++nt)
            #pragma unroll
            for (int mt = 0; mt < 2; ++mt)
                sc_[nt][mt] = (floatx4){0.f, 0.f, 0.f, 0.f};

        // 768-dim contraction; A coalesced from global, B from LDS
        #pragma unroll
        for (int c = 0; c < 24; ++c) {
            const short8 a0 = *(const short8*)(A + c * 1024);
            const short8 a1 = *(const short8*)(A + c * 1024 + 512);
            const short8 b0 = *(const short8*)(qb + (c >> 2) * 136 + (c & 3) * 32);
            const short8 b1 = *(const short8*)(qb + (16 + (c >> 2)) * 136 + (c & 3) * 32);
            sc_[0][0] = __builtin_amdgcn_mfma_f32_16x16x32_bf16(a0, b0, sc_[0][0], 0, 0, 0);
            sc_[0][1] = __builtin_amdgcn_mfma_f32_16x16x32_bf16(a0, b1, sc_[0][1], 0, 0, 0);
            sc_[1][0] = __builtin_amdgcn_mfma_f32_16x16x32_bf16(a1, b0, sc_[1][0], 0, 0, 0);
            sc_[1][1] = __builtin_amdgcn_mfma_f32_16x16x32_bf16(a1, b1, sc_[1][1], 0, 0, 0);
        }

        // ---- online softmax; lane l15 = q-row, elements span k ------------
        const bool need_corr = (kt >= qt - 1);
        float al[2];
        short8 pfrag[2];
        #pragma unroll
        for (int mt = 0; mt < 2; ++mt) {
            const int qrow = q0 + mt * 16 + l15;
            float lg[8];
            float mx = -1e30f;
            #pragma unroll
            for (int nt = 0; nt < 2; ++nt)
                #pragma unroll
                for (int rg = 0; rg < 4; ++rg) {
                    const int kcol = k0 + nt * 16 + qd * 4 + rg;
                    float v = sc_[nt][mt][rg];
                    if (need_corr) {
                        const int dd = qrow - kcol;
                        if (dd >= 0 && dd <= 10) v -= Cb[(qrow << 4) + dd];
                    }
                    const int jj = nt * 4 + rg;
                    lg[jj] = (kcol <= qrow) ? v : -1e30f;
                    mx = fmaxf(mx, lg[jj]);
                }
            mx = fmaxf(mx, __shfl_xor(mx, 16));
            mx = fmaxf(mx, __shfl_xor(mx, 32));
            const float nm = fmaxf(m_run[mt], mx);
            al[mt] = __expf(m_run[mt] - nm);
            float sum = 0.f;
            short8 pbv;
            #pragma unroll
            for (int jj = 0; jj < 8; ++jj) {
                const float p = __expf(lg[jj] - nm);
                sum += p;
                pbv[jj] = (short)f2b(p);
            }
            sum += __shfl_xor(sum, 16);
            sum += __shfl_xor(sum, 32);
            l_run[mt] = l_run[mt] * al[mt] + sum;
            m_run[mt] = nm;
            pfrag[mt] = pbv;
        }

        // rescale accumulator: alpha for acc row qd*4+rg lives on lane qd*4+rg
        #pragma unroll
        for (int mt = 0; mt < 2; ++mt)
            #pragma unroll
            for (int rg = 0; rg < 4; ++rg) {
                const float af = __shfl(al[mt], qd * 4 + rg, 64);
                #pragma unroll
                for (int nd = 0; nd < 8; ++nd)
                    acc[mt][nd][rg] *= af;
            }

        // ---- P @ V via MFMA (pfrag element order matches permuted VhF) ----
        #pragma unroll
        for (int nd = 0; nd < 8; ++nd)
            #pragma unroll
            for (int mt = 0; mt < 2; ++mt)
                acc[mt][nd] = __builtin_amdgcn_mfma_f32_16x16x32_bf16(pfrag[mt], vf[nd], acc[mt][nd], 0, 0, 0);
    }

    // ---- merge the 4 waves' partials ---------------------------------------
    if (qd == 0) {
        m_all[wv][l15] = m_run[0]; m_all[wv][l15 + 16] = m_run[1];
        l_all[wv][l15] = l_run[0]; l_all[wv][l15 + 16] = l_run[1];
    }
    __syncthreads();
    if (tid < 32) {
        float ms = -INFINITY;
        #pragma unroll
        for (int w = 0; w < NW; ++w) ms = fmaxf(ms, m_all[w][tid]);
        float ls = 0.f;
        #pragma unroll
        for (int w = 0; w < NW; ++w) ls += __expf(m_all[w][tid] - ms) * l_all[w][tid];
        ms_s[tid] = ms;
        inv_s[tid] = 1.f / ls;
    }
    __syncthreads();
    for (int w = 0; w < NW; ++w) {
        if (wv == w) {
            #pragma unroll
            for (int mt = 0; mt < 2; ++mt) {
                #pragma unroll
                for (int rg = 0; rg < 4; ++rg) {
                    const int row = mt * 16 + qd * 4 + rg;
                    const float f = __expf(m_all[wv][row] - ms_s[row]);
                    #pragma unroll
                    for (int nd = 0; nd < 8; ++nd) {
                        const float val = acc[mt][nd][rg] * f;
                        if (w == 0) u.oacc[row][nd * 16 + l15] = val;
                        else        u.oacc[row][nd * 16 + l15] += val;
                    }
                }
            }
        }
        __syncthreads();
    }

    // ---- normalize + store --------------------------------------------------
    {
        const int r = tid >> 3;
        const int c0 = (tid & 7) * 16;
        const float inv = inv_s[r];
        float* orow = O + ((size_t)bh * S_ + q0 + r) * D_ + c0;
        #pragma unroll
        for (int g = 0; g < 4; ++g) {
            float4 o;
            o.x = u.oacc[r][c0 + g * 4 + 0] * inv;
            o.y = u.oacc[r][c0 + g * 4 + 1] * inv;
            o.z = u.oacc[r][c0 + g * 4 + 2] * inv;
            o.w = u.oacc[r][c0 + g * 4 + 3] * inv;
            *(float4*)(orow + g * 4) = o;
        }
    }
}

extern "C" void kernel_launch(void* const* d_in, const int* in_sizes, int n_in,
                              void* d_out, int out_size, void* d_ws, size_t ws_size,
                              hipStream_t stream) {
    const float* Q = (const float*)d_in[0];
    const float* K = (const float*)d_in[1];
    const float* V = (const float*)d_in[2];
    const float* W = (const float*)d_in[3];
    float* O = (float*)d_out;

    // ws layout (~52 MB)
    unsigned short* Qp  = (unsigned short*)d_ws;                        // 24*1040*128*2 = 6,389,760
    unsigned short* KhF = (unsigned short*)((char*)d_ws + 6389760);     // 768*24576*2   = 37,748,736
    unsigned short* VhF = (unsigned short*)((char*)d_ws + 44138496);    // 768*4096*2    = 6,291,456
    float*          Cr  = (float*)((char*)d_ws + 50429952);             // 24*1024*16*4  = 1,572,864

    prep_kernel<<<dim3(NB_PREP), dim3(256), 0, stream>>>(Q, K, V, W, Qp, KhF, VhF, Cr);
    conv_attn_mfma<<<dim3(BH_ * (S_ / TQ)), dim3(256), 0, stream>>>(Qp, KhF, VhF, Cr, O);
}

// Round 3
// 285.820 us; speedup vs baseline: 1.4654x; 1.2216x over previous
//
#include <hip/hip_runtime.h>
#include <hip/hip_bf16.h>
#include <math.h>

#define B_ 2
#define H_ 12
#define S_ 1024
#define D_ 128
#define BH_ (B_ * H_)
#define SCALE 0.08838834764831843f

#define QPAD 16
#define QROWS (S_ + QPAD)          /* 1040 */

/* merged prepass grid segmentation */
#define NB_KH   768                /* 24 bh * 32 k-tiles */
#define NB_QP   3120               /* 24*1040*128 / 1024 */
#define NB_VT   3072               /* 24*32*4 */
#define NB_CORR 384                /* 24*16 */
#define NB_PREP (NB_KH + NB_QP + NB_VT + NB_CORR)

typedef __attribute__((ext_vector_type(8))) short short8;
typedef __attribute__((ext_vector_type(4))) float floatx4;

__device__ __forceinline__ unsigned short f2b(float f) {
    return __builtin_bit_cast(unsigned short, __float2bfloat16(f));
}

// ---- merged prepass ---------------------------------------------------------
// KH: Khat fragment-major. Block (bh*32+kt) is 24576 ushorts: [c24][nt2][ln64][e8]
//     holding Khat[k=kt*32+nt*16+(ln&15)][col=c*32+(ln>>4)*8+e],
//     Khat[k][i*128+d] = sum_j W[h][i][j]*SCALE * K[k+j-5][d].  (no LDS: direct store)
// QP: Q -> bf16 row-major, 16 zero rows of top padding.
// VT: VhF[bh*32+kt][nd8][ln64][e8] = V (sigma-permuted for swapped-MFMA PV).
// CORR: Corr[bh][q][d] = sum_{i,j: j-i>d} Ws[i,j]*(Q[q-5+i].K[q-5+i+(j-i-d)])
__global__ __launch_bounds__(256) void prep_kernel(
    const float* __restrict__ Q, const float* __restrict__ K,
    const float* __restrict__ V, const float* __restrict__ W,
    unsigned short* __restrict__ Qp, unsigned short* __restrict__ KhF,
    unsigned short* __restrict__ VhF, float* __restrict__ Corr)
{
    __shared__ union {
        float vt_ls[32][33];
        float band[69][16];
    } sm;
    const int blk = blockIdx.x;
    const int tid = threadIdx.x;

    if (blk < NB_KH) {
        const int wgk = (blk & 7) * 96 + (blk >> 3);   // XCD-cluster: 3 bh / XCD
        const int bh = wgk >> 5, ktile = wgk & 31;
        const int h = bh % H_;
        const int k0 = ktile * 32;
        const float* Kb = K + (size_t)bh * S_ * D_;
        const float* Wh = W + h * 66;
        const size_t obase = (size_t)wgk * 24576;
        #pragma unroll
        for (int it = 0; it < 4; ++it) {
            const int p = tid + it * 256;
            const int r = p >> 5;
            const int d0 = (p & 31) * 4;
            const int k = k0 + r;
            float a[6][4];
            #pragma unroll
            for (int i = 0; i < 6; ++i)
                #pragma unroll
                for (int t = 0; t < 4; ++t) a[i][t] = 0.f;
            if (k >= 5 && k <= S_ - 6) {          // interior fast path
                #pragma unroll
                for (int j = 0; j < 11; ++j) {
                    const float4 kv = *(const float4*)(Kb + (size_t)(k + j - 5) * D_ + d0);
                    #pragma unroll
                    for (int i = 0; i < 6; ++i) {
                        const float w = Wh[i * 11 + j];
                        a[i][0] += w * kv.x; a[i][1] += w * kv.y;
                        a[i][2] += w * kv.z; a[i][3] += w * kv.w;
                    }
                }
            } else {
                #pragma unroll
                for (int j = 0; j < 11; ++j) {
                    const int kr = k + j - 5;
                    if (kr >= 0 && kr < S_) {
                        const float4 kv = *(const float4*)(Kb + (size_t)kr * D_ + d0);
                        #pragma unroll
                        for (int i = 0; i < 6; ++i) {
                            const float w = Wh[i * 11 + j];
                            a[i][0] += w * kv.x; a[i][1] += w * kv.y;
                            a[i][2] += w * kv.z; a[i][3] += w * kv.w;
                        }
                    }
                }
            }
            const int nt = r >> 4;
            const int ln2 = (((d0 & 31) >> 3) << 4) | (r & 15);
            const int e0 = d0 & 7;
            const int cc = d0 >> 5;
            #pragma unroll
            for (int i = 0; i < 6; ++i) {
                const int c = i * 4 + cc;
                ushort4 o;
                o.x = f2b(a[i][0] * SCALE); o.y = f2b(a[i][1] * SCALE);
                o.z = f2b(a[i][2] * SCALE); o.w = f2b(a[i][3] * SCALE);
                *(ushort4*)(KhF + obase + (size_t)((c * 2 + nt) * 64 + ln2) * 8 + e0) = o;
            }
        }
    } else if (blk < NB_KH + NB_QP) {
        const int idx = (blk - NB_KH) * 256 + tid;
        const size_t e0 = (size_t)idx * 4;
        const int bh = (int)(e0 / ((size_t)QROWS * D_));
        const int rem = (int)(e0 - (size_t)bh * QROWS * D_);
        const int r = rem / D_;
        const int d = rem - r * D_;
        const int sr = r - QPAD;
        float4 v = make_float4(0.f, 0.f, 0.f, 0.f);
        if (sr >= 0 && sr < S_)
            v = *(const float4*)(Q + ((size_t)bh * S_ + sr) * D_ + d);
        ushort4 o; o.x = f2b(v.x); o.y = f2b(v.y); o.z = f2b(v.z); o.w = f2b(v.w);
        *(ushort4*)(Qp + ((size_t)bh * QROWS + r) * D_ + d) = o;
    } else if (blk < NB_KH + NB_QP + NB_VT) {
        const int b2 = blk - (NB_KH + NB_QP);
        const int dt = b2 & 3, ktl = (b2 >> 2) & 31, bh = b2 >> 7;
        const int lk = tid >> 3, ld = (tid & 7) * 4;
        const float4 v4 = *(const float4*)(V + ((size_t)bh * S_ + ktl * 32 + lk) * D_ + dt * 32 + ld);
        sm.vt_ls[lk][ld + 0] = v4.x; sm.vt_ls[lk][ld + 1] = v4.y;
        sm.vt_ls[lk][ld + 2] = v4.z; sm.vt_ls[lk][ld + 3] = v4.w;
        __syncthreads();
        const int lk2 = tid >> 3, lc = (tid & 7) * 4;
        const int pb = ((lc >> 3) << 2) | (((lc >> 2) & 1) << 4);   // sigma
        const int d = dt * 32 + lk2;
        const int nd = d >> 4, l15v = d & 15;
        ushort4 o;
        o.x = f2b(sm.vt_ls[pb + 0][lk2]); o.y = f2b(sm.vt_ls[pb + 1][lk2]);
        o.z = f2b(sm.vt_ls[pb + 2][lk2]); o.w = f2b(sm.vt_ls[pb + 3][lk2]);
        const size_t addr = ((size_t)((bh * 32 + ktl) * 8 + nd) * 64
                             + (lc >> 3) * 16 + l15v) * 8 + (lc & 7);
        *(ushort4*)(VhF + addr) = o;
    } else {
        const int cb = blk - (NB_KH + NB_QP + NB_VT);
        const int bh = cb >> 4, q0c = (cb & 15) * 64;
        const int h = bh % H_;
        for (int s = tid; s < 69 * 16; s += 256) {
            const int r = s >> 4, dsl = s & 15;
            float v = 0.f;
            if (dsl < 10) {
                const int qp = q0c - 5 + r, delta = dsl + 1;
                if (qp >= 0 && qp + delta < S_) {
                    const float4* qr = (const float4*)(Q + ((size_t)bh * S_ + qp) * D_);
                    const float4* kr = (const float4*)(K + ((size_t)bh * S_ + qp + delta) * D_);
                    #pragma unroll 8
                    for (int c = 0; c < 32; ++c) {
                        const float4 a = qr[c], b = kr[c];
                        v += a.x * b.x + a.y * b.y + a.z * b.z + a.w * b.w;
                    }
                }
            }
            sm.band[r][dsl] = v;
        }
        __syncthreads();
        for (int e = tid; e < 64 * 16; e += 256) {
            const int ql = e >> 4, d = e & 15;
            float v = 0.f;
            if (d <= 10) {
                for (int i2 = 0; i2 < 6; ++i2)
                    for (int j = i2 + d + 1; j < 11; ++j)
                        v += W[h * 66 + i2 * 11 + j] * SCALE * sm.band[ql + i2][j - i2 - d - 1];
            }
            Corr[((size_t)bh << 14) + ((size_t)(q0c + ql) << 4) + d] = v;
        }
    }
}

// ---- main fused kernel ------------------------------------------------------
// Block = 4 waves x 32 q-rows (TQ=128). Khat tile double-buffered in LDS via
// global_load_lds; Q fragments register-resident; each wave owns its full
// k-range (no cross-wave merge).
__global__ __launch_bounds__(256, 1) void conv_attn_mfma(
    const unsigned short* __restrict__ Qp,   // [24][1040][128] bf16
    const unsigned short* __restrict__ KhF,  // fragment-major Khat
    const unsigned short* __restrict__ VhF,  // fragment-major permuted V
    const float* __restrict__ Corr,          // [24][1024][16]  f32
    float* __restrict__ O)                   // [24][1024][128] f32
{
    __shared__ __align__(16) unsigned short kh[2][24576];   // 96 KiB dbuf

    const int tid = threadIdx.x;
    const int wv = tid >> 6;
    const int ln = tid & 63;
    const int l15 = ln & 15;
    const int qd = ln >> 4;

    // 192 blocks = 8 XCD x 3 bh x 8 q-blocks; heavy q-blocks first per bh
    const int bid = blockIdx.x;
    const int wg = (bid & 7) * 24 + (bid >> 3);
    const int bh = wg >> 3;
    const int qb = 7 - (wg & 7);
    const int qw0 = qb * 128 + wv * 32;      // this wave's first q-row
    const int ktb = 4 * qb + 3;              // block's last k-tile
    const int ktw = 4 * qb + wv;             // this wave's last k-tile

    const unsigned short* Khb = KhF + (size_t)(bh * 32) * 24576;
    const unsigned short* Vhb = VhF + (size_t)(bh * 32) * 4096 + ln * 8;
    const float* Cb = Corr + ((size_t)bh << 14);

#define STAGE(bi, ktile)                                                        \
    {                                                                           \
        const unsigned short* _s = Khb + (size_t)(ktile) * 24576 + wv * 6144 + ln * 8; \
        unsigned short* _d = &kh[bi][wv * 6144];                                \
        _Pragma("unroll")                                                       \
        for (int _g = 0; _g < 12; ++_g)                                         \
            __builtin_amdgcn_global_load_lds(                                   \
                (const __attribute__((address_space(1))) void*)(_s + _g * 512), \
                (__attribute__((address_space(3))) void*)(_d + _g * 512),       \
                16, 0, 0);                                                      \
    }

    STAGE(0, 0);

    // ---- Q B-fragments: register-resident for the whole block --------------
    short8 qf[2][6][4];
    {
        const unsigned short* qbase =
            Qp + ((size_t)bh * QROWS + qw0 + 11 + l15) * D_ + qd * 8;
        #pragma unroll
        for (int mt = 0; mt < 2; ++mt)
            #pragma unroll
            for (int i = 0; i < 6; ++i)
                #pragma unroll
                for (int kc = 0; kc < 4; ++kc)
                    qf[mt][i][kc] = *(const short8*)(qbase + (size_t)(mt * 16 + i) * D_ + kc * 32);
    }

    floatx4 acc[2][8];
    #pragma unroll
    for (int mt = 0; mt < 2; ++mt)
        #pragma unroll
        for (int nd = 0; nd < 8; ++nd)
            acc[mt][nd] = (floatx4){0.f, 0.f, 0.f, 0.f};
    float m_run[2] = {-INFINITY, -INFINITY};
    float l_run[2] = {0.f, 0.f};

    __syncthreads();   // tile 0 staged (barrier drains vmcnt)

    for (int kt = 0; kt <= ktb; ++kt) {
        if (kt < ktb) STAGE((kt + 1) & 1, kt + 1);   // prefetch next tile

        if (kt <= ktw) {
            const int k0 = kt * 32;
            const unsigned short* A = &kh[kt & 1][ln * 8];

            short8 vf[8];
            #pragma unroll
            for (int nd = 0; nd < 8; ++nd)
                vf[nd] = *(const short8*)(Vhb + (size_t)kt * 4096 + nd * 512);

            floatx4 sc_[2][2];   // [nt][mt]: rows=k (qd*4+rg), cols=q (l15)
            #pragma unroll
            for (int nt = 0; nt < 2; ++nt)
                #pragma unroll
                for (int mt = 0; mt < 2; ++mt)
                    sc_[nt][mt] = (floatx4){0.f, 0.f, 0.f, 0.f};

            #pragma unroll
            for (int c = 0; c < 24; ++c) {
                const short8 a0 = *(const short8*)(A + c * 1024);
                const short8 a1 = *(const short8*)(A + c * 1024 + 512);
                const short8 b0 = qf[0][c >> 2][c & 3];
                const short8 b1 = qf[1][c >> 2][c & 3];
                sc_[0][0] = __builtin_amdgcn_mfma_f32_16x16x32_bf16(a0, b0, sc_[0][0], 0, 0, 0);
                sc_[0][1] = __builtin_amdgcn_mfma_f32_16x16x32_bf16(a0, b1, sc_[0][1], 0, 0, 0);
                sc_[1][0] = __builtin_amdgcn_mfma_f32_16x16x32_bf16(a1, b0, sc_[1][0], 0, 0, 0);
                sc_[1][1] = __builtin_amdgcn_mfma_f32_16x16x32_bf16(a1, b1, sc_[1][1], 0, 0, 0);
            }

            // ---- online softmax; lane l15 = q-row, elements span k --------
            const bool need_corr = (kt >= ktw - 1);
            float al[2];
            short8 pfrag[2];
            #pragma unroll
            for (int mt = 0; mt < 2; ++mt) {
                const int qrow = qw0 + mt * 16 + l15;
                float lg[8];
                float mx = -1e30f;
                #pragma unroll
                for (int nt = 0; nt < 2; ++nt)
                    #pragma unroll
                    for (int rg = 0; rg < 4; ++rg) {
                        const int kcol = k0 + nt * 16 + qd * 4 + rg;
                        float v = sc_[nt][mt][rg];
                        if (need_corr) {
                            const int dd = qrow - kcol;
                            if (dd >= 0 && dd <= 10) v -= Cb[(qrow << 4) + dd];
                        }
                        const int jj = nt * 4 + rg;
                        lg[jj] = (kcol <= qrow) ? v : -1e30f;
                        mx = fmaxf(mx, lg[jj]);
                    }
                mx = fmaxf(mx, __shfl_xor(mx, 16));
                mx = fmaxf(mx, __shfl_xor(mx, 32));
                const float nm = fmaxf(m_run[mt], mx);
                al[mt] = __expf(m_run[mt] - nm);
                float sum = 0.f;
                short8 pbv;
                #pragma unroll
                for (int jj = 0; jj < 8; ++jj) {
                    const float p = __expf(lg[jj] - nm);
                    sum += p;
                    pbv[jj] = (short)f2b(p);
                }
                sum += __shfl_xor(sum, 16);
                sum += __shfl_xor(sum, 32);
                l_run[mt] = l_run[mt] * al[mt] + sum;
                m_run[mt] = nm;
                pfrag[mt] = pbv;
            }

            // rescale: alpha for acc row qd*4+rg lives on lane qd*4+rg
            #pragma unroll
            for (int mt = 0; mt < 2; ++mt)
                #pragma unroll
                for (int rg = 0; rg < 4; ++rg) {
                    const float af = __shfl(al[mt], qd * 4 + rg, 64);
                    #pragma unroll
                    for (int nd = 0; nd < 8; ++nd)
                        acc[mt][nd][rg] *= af;
                }

            // ---- P @ V (pfrag order matches sigma-permuted VhF) -----------
            #pragma unroll
            for (int nd = 0; nd < 8; ++nd)
                #pragma unroll
                for (int mt = 0; mt < 2; ++mt)
                    acc[mt][nd] = __builtin_amdgcn_mfma_f32_16x16x32_bf16(pfrag[mt], vf[nd], acc[mt][nd], 0, 0, 0);
        }

        __syncthreads();   // next tile staged; current buffer free for reuse
    }

    // ---- normalize + store (no cross-wave merge needed) --------------------
    {
        float inv[2] = {1.f / l_run[0], 1.f / l_run[1]};
        #pragma unroll
        for (int mt = 0; mt < 2; ++mt)
            #pragma unroll
            for (int rg = 0; rg < 4; ++rg) {
                const float iv = __shfl(inv[mt], qd * 4 + rg, 64);
                const int row = qw0 + mt * 16 + qd * 4 + rg;
                float* orow = O + ((size_t)bh * S_ + row) * D_;
                #pragma unroll
                for (int nd = 0; nd < 8; ++nd)
                    orow[nd * 16 + l15] = acc[mt][nd][rg] * iv;
            }
    }
#undef STAGE
}

extern "C" void kernel_launch(void* const* d_in, const int* in_sizes, int n_in,
                              void* d_out, int out_size, void* d_ws, size_t ws_size,
                              hipStream_t stream) {
    const float* Q = (const float*)d_in[0];
    const float* K = (const float*)d_in[1];
    const float* V = (const float*)d_in[2];
    const float* W = (const float*)d_in[3];
    float* O = (float*)d_out;

    // ws layout (~52 MB)
    unsigned short* Qp  = (unsigned short*)d_ws;                        // 24*1040*128*2 = 6,389,760
    unsigned short* KhF = (unsigned short*)((char*)d_ws + 6389760);     // 768*24576*2   = 37,748,736
    unsigned short* VhF = (unsigned short*)((char*)d_ws + 44138496);    // 768*4096*2    = 6,291,456
    float*          Cr  = (float*)((char*)d_ws + 50429952);             // 24*1024*16*4  = 1,572,864

    prep_kernel<<<dim3(NB_PREP), dim3(256), 0, stream>>>(Q, K, V, W, Qp, KhF, VhF, Cr);
    conv_attn_mfma<<<dim3(BH_ * 8), dim3(256), 0, stream>>>(Qp, KhF, VhF, Cr, O);
}